// Round 3
// baseline (632.864 us; speedup 1.0000x reference)
//
#include <hip/hip_runtime.h>

// SwitchPolicyValueNetwork — round 3.
// m97-verified GEMM structure everywhere: BK=32, single 16KB LDS buffer,
// global_load_lds(16B) async staging for bf16 operands, in-loop fp32->bf16
// convert staging for fp32 weight operands (no separate cvt kernels),
// XOR-swizzled LDS chunks (bank-balanced ds_read_b128), 2 barriers/iter.
// Pipeline: bucket -> k_pre -> k_expert (grouped, selected expert only) -> k_post.
// 4 dispatches total. ws use ~32.1 MB (X1, Z bf16 + bucket arrays).

#define Bsz 4096
#define INd 1024
#define Hd  2048
#define OUTd 1024
#define NEXP 16

typedef short bf16x8 __attribute__((ext_vector_type(8)));
typedef float f32x4 __attribute__((ext_vector_type(4)));
typedef unsigned short u16;

__device__ __forceinline__ u16 f2bf(float f) {
  unsigned u = __float_as_uint(f);
  u += 0x7FFF + ((u >> 16) & 1);   // RNE
  return (u16)(u >> 16);
}

__device__ __forceinline__ float fast_tanh(float x) {
  float ax = fabsf(x);
  float e = __expf(2.0f * ax);     // saturates to 1 for large |x|
  float t = 1.0f - 2.0f / (e + 1.0f);
  return x < 0.0f ? -t : t;
}

#define GLL16(g, l)                                                            \
  __builtin_amdgcn_global_load_lds(                                            \
      (const __attribute__((address_space(1))) unsigned int*)(g),              \
      (__attribute__((address_space(3))) unsigned int*)(l), 16, 0, 0)

// swizzle: logical 16B chunk q of row r lives at physical chunk q ^ ((r^(r>>2))&3)
__device__ __forceinline__ int swz(int r) { return (r ^ (r >> 2)) & 3; }

// ---- stage 128x32 bf16 tile via async global->LDS (2 chunks/thread) ----
// physical LDS slot s = t + 256p (16B units); row = s>>2, phys chunk = t&3.
__device__ __forceinline__ void stage_bf16_128(const u16* g, int ldk, u16* lds, int t) {
  const int r0 = t >> 2;
  const int c = (t & 3) ^ swz(r0);          // p-independent (64p doesn't touch low bits)
#pragma unroll
  for (int p = 0; p < 2; ++p)
    GLL16(g + (size_t)(r0 + 64 * p) * ldk + c * 8, lds + ((t + 256 * p) << 3));
}

// ---- stage 64x32 bf16 tile (1 chunk/thread) ----
__device__ __forceinline__ void stage_bf16_64(const u16* g, int ldk, u16* lds, int t) {
  const int r = t >> 2;
  const int c = (t & 3) ^ swz(r);
  GLL16(g + (size_t)r * ldk + c * 8, lds + (t << 3));
}

// ---- gathered 128x32 bf16 tile from X1 (per-row indices; tail -> zero chunk) ----
__device__ __forceinline__ void stage_gather(const u16* X1k, const int rg[2],
                                             const u16* zeroc, u16* lds, int t) {
  const int r0 = t >> 2;
  const int c = (t & 3) ^ swz(r0);
#pragma unroll
  for (int p = 0; p < 2; ++p) {
    const u16* g = (rg[p] >= 0) ? X1k + (size_t)rg[p] * Hd + c * 8 : zeroc;
    GLL16(g, lds + ((t + 256 * p) << 3));
  }
}

// ---- stage 128x32 tile from fp32 source, converting in-loop ----
__device__ __forceinline__ void stage_f32_128(const float* g, int ldk, u16* lds, int t) {
  const int r0 = t >> 2;
  const int c = (t & 3) ^ swz(r0);
#pragma unroll
  for (int p = 0; p < 2; ++p) {
    const float* src = g + (size_t)(r0 + 64 * p) * ldk + c * 8;
    float4 a = *(const float4*)src;
    float4 b = *(const float4*)(src + 4);
    bf16x8 o;
    o[0] = (short)f2bf(a.x); o[1] = (short)f2bf(a.y);
    o[2] = (short)f2bf(a.z); o[3] = (short)f2bf(a.w);
    o[4] = (short)f2bf(b.x); o[5] = (short)f2bf(b.y);
    o[6] = (short)f2bf(b.z); o[7] = (short)f2bf(b.w);
    *(bf16x8*)&lds[(t + 256 * p) << 3] = o;
  }
}

// ---- one BK=32 tile of MFMAs: MI x 4 per wave ----
template <int MI>
__device__ __forceinline__ void compute_tile(const u16* As, const u16* Bs,
                                             int wm, int wn, int fr, int co,
                                             f32x4 (&acc)[MI][4]) {
  bf16x8 af[MI], bq[4];
#pragma unroll
  for (int i = 0; i < MI; ++i) af[i] = *(const bf16x8*)&As[(wm + 16 * i + fr) * 32 + co];
#pragma unroll
  for (int j = 0; j < 4; ++j) bq[j] = *(const bf16x8*)&Bs[(wn + 16 * j + fr) * 32 + co];
#pragma unroll
  for (int i = 0; i < MI; ++i)
#pragma unroll
    for (int j = 0; j < 4; ++j)
      acc[i][j] = __builtin_amdgcn_mfma_f32_16x16x32_bf16(af[i], bq[j], acc[i][j], 0, 0, 0);
}

// ---------------- bucketing (counting sort) + zero-chunk init ----------------
__global__ __launch_bounds__(256) void k_bucket(const int* __restrict__ idx,
                                                int* __restrict__ offs,
                                                int* __restrict__ rows,
                                                int* __restrict__ zc) {
  __shared__ int cnt[NEXP];
  __shared__ int base[NEXP];
  int t = threadIdx.x;
  if (t < 16) zc[t] = 0;
  if (t < NEXP) cnt[t] = 0;
  __syncthreads();
  for (int b = t; b < Bsz; b += 256) atomicAdd(&cnt[idx[b]], 1);
  __syncthreads();
  if (t == 0) {
    int s = 0;
    for (int e = 0; e < NEXP; ++e) { base[e] = s; offs[e] = s; s += cnt[e]; }
    offs[NEXP] = s;
  }
  __syncthreads();
  for (int b = t; b < Bsz; b += 256) {
    int e = idx[b];
    int p = atomicAdd(&base[e], 1);
    rows[p] = b;
  }
}

// ---------------- GEMM1: X1 = tanh(obs @ pre_w^T + pre_b), bf16 out ----------------
__global__ __launch_bounds__(256) void k_pre(const float* __restrict__ obs,
                                             const float* __restrict__ pre_w,
                                             const float* __restrict__ pre_b,
                                             u16* __restrict__ X1) {
  __shared__ u16 As[128 * 32];
  __shared__ u16 Bs[128 * 32];
  const int tid = threadIdx.x, lane = tid & 63, wv = tid >> 6;
  const int wm = (wv >> 1) << 6, wn = (wv & 1) << 6;
  const int fr = lane & 15, fq = lane >> 4;
  const int co = (fq ^ swz(fr)) << 3;
  const int n0 = blockIdx.x * 128, m0 = blockIdx.y * 128;
  f32x4 acc[4][4] = {};

  const float* Ab = obs + (size_t)m0 * INd;
  const float* Bb = pre_w + (size_t)n0 * INd;
  for (int k0 = 0; k0 < INd; k0 += 32) {
    stage_f32_128(Ab + k0, INd, As, tid);
    stage_f32_128(Bb + k0, INd, Bs, tid);
    __syncthreads();
    compute_tile<4>(As, Bs, wm, wn, fr, co, acc);
    __syncthreads();
  }

#pragma unroll
  for (int j = 0; j < 4; ++j) {
    int col = n0 + wn + 16 * j + fr;
    float bias = pre_b[col];
#pragma unroll
    for (int i = 0; i < 4; ++i) {
      int rb2 = m0 + wm + 16 * i + fq * 4;
#pragma unroll
      for (int r = 0; r < 4; ++r)
        X1[(size_t)(rb2 + r) * Hd + col] = f2bf(fast_tanh(acc[i][j][r] + bias));
    }
  }
}

// ------- GEMM2 (grouped): Z[row] = tanh(X1[row] @ W_e^T + b_e) -------
__global__ __launch_bounds__(256) void k_expert(const u16* __restrict__ X1,
                                                const float* __restrict__ ew,
                                                const float* __restrict__ eb,
                                                const int* __restrict__ offs,
                                                const int* __restrict__ rows,
                                                const u16* __restrict__ zeroc,
                                                u16* __restrict__ Z) {
  const int e = blockIdx.y >> 5, rt = blockIdx.y & 31;
  const int seg = offs[e], cnt = offs[e + 1] - seg;
  const int tbase = rt * 128;
  if (tbase >= cnt) return;                 // block-uniform early exit
  const int nval = min(128, cnt - tbase);
  const int n0 = blockIdx.x * 128;

  __shared__ u16 As[128 * 32];
  __shared__ u16 Bs[128 * 32];
  const int tid = threadIdx.x, lane = tid & 63, wv = tid >> 6;
  const int wm = (wv >> 1) << 6, wn = (wv & 1) << 6;
  const int fr = lane & 15, fq = lane >> 4;
  const int co = (fq ^ swz(fr)) << 3;

  int rg[2];
  {
    const int r0 = tid >> 2;
#pragma unroll
    for (int p = 0; p < 2; ++p) {
      int ar = r0 + 64 * p;
      rg[p] = (ar < nval) ? rows[seg + tbase + ar] : -1;
    }
  }

  const float* We = ew + (size_t)e * Hd * Hd + (size_t)n0 * Hd;
  f32x4 acc[4][4] = {};

  for (int k0 = 0; k0 < Hd; k0 += 32) {
    stage_gather(X1 + k0, rg, zeroc, As, tid);
    stage_f32_128(We + k0, Hd, Bs, tid);
    __syncthreads();
    compute_tile<4>(As, Bs, wm, wn, fr, co, acc);
    __syncthreads();
  }

#pragma unroll
  for (int i = 0; i < 4; ++i) {
#pragma unroll
    for (int r = 0; r < 4; ++r) {
      int arow = wm + 16 * i + fq * 4 + r;
      if (arow < nval) {
        int orow = rows[seg + tbase + arow];
#pragma unroll
        for (int j = 0; j < 4; ++j) {
          int col = n0 + wn + 16 * j + fr;
          float bias = eb[(size_t)e * Hd + col];
          Z[(size_t)orow * Hd + col] = f2bf(fast_tanh(acc[i][j][r] + bias));
        }
      }
    }
  }
}

// ---------------- GEMM3: out = tanh(Z @ post_w^T + post_b), BM=64 ----------------
__global__ __launch_bounds__(256) void k_post(const u16* __restrict__ Z,
                                              const float* __restrict__ pw,
                                              const float* __restrict__ pb,
                                              float* __restrict__ out) {
  __shared__ u16 As[64 * 32];
  __shared__ u16 Bs[128 * 32];
  const int tid = threadIdx.x, lane = tid & 63, wv = tid >> 6;
  const int wm = (wv >> 1) << 5, wn = (wv & 1) << 6;   // wave tile 32x64
  const int fr = lane & 15, fq = lane >> 4;
  const int co = (fq ^ swz(fr)) << 3;
  const int n0 = blockIdx.x * 128, m0 = blockIdx.y * 64;
  f32x4 acc[2][4] = {};

  const u16* Ab = Z + (size_t)m0 * Hd;
  const float* Bb = pw + (size_t)n0 * Hd;
  for (int k0 = 0; k0 < Hd; k0 += 32) {
    stage_bf16_64(Ab + k0, Hd, As, tid);
    stage_f32_128(Bb + k0, Hd, Bs, tid);
    __syncthreads();
    compute_tile<2>(As, Bs, wm, wn, fr, co, acc);
    __syncthreads();
  }

#pragma unroll
  for (int j = 0; j < 4; ++j) {
    int col = n0 + wn + 16 * j + fr;
    float bias = pb[col];
#pragma unroll
    for (int i = 0; i < 2; ++i) {
      int rb2 = m0 + wm + 16 * i + fq * 4;
#pragma unroll
      for (int r = 0; r < 4; ++r)
        out[(size_t)(rb2 + r) * OUTd + col] = fast_tanh(acc[i][j][r] + bias);
    }
  }
}

extern "C" void kernel_launch(void* const* d_in, const int* in_sizes, int n_in,
                              void* d_out, int out_size, void* d_ws, size_t ws_size,
                              hipStream_t stream) {
  const float* obs   = (const float*)d_in[0];
  const int*   sw    = (const int*)d_in[1];
  const float* pre_w = (const float*)d_in[2];
  const float* pre_b = (const float*)d_in[3];
  const float* ew    = (const float*)d_in[4];
  const float* eb    = (const float*)d_in[5];
  const float* pw    = (const float*)d_in[6];
  const float* pb    = (const float*)d_in[7];
  float* out = (float*)d_out;

  char* ws = (char*)d_ws;
  int* offs  = (int*)ws;
  int* rows  = (int*)(ws + 128);
  u16* zeroc = (u16*)(ws + 128 + 16384);
  const size_t MISC = 65536;
  u16* X1 = (u16*)(ws + MISC);
  u16* Zb = (u16*)(ws + MISC + ((size_t)Bsz * Hd * 2));

  k_bucket<<<dim3(1), dim3(256), 0, stream>>>(sw, offs, rows, (int*)zeroc);
  k_pre<<<dim3(Hd / 128, Bsz / 128), dim3(256), 0, stream>>>(obs, pre_w, pre_b, X1);
  k_expert<<<dim3(Hd / 128, NEXP * 32), dim3(256), 0, stream>>>(X1, ew, eb, offs, rows, zeroc, Zb);
  k_post<<<dim3(OUTd / 128, Bsz / 64), dim3(256), 0, stream>>>(Zb, pw, pb, out);
}